// Round 1
// baseline (62.418 us; speedup 1.0000x reference)
//
#include <hip/hip_runtime.h>
#include <math.h>

// Problem constants (match reference setup_inputs)
#define BB 8
#define NN 2048
#define BN (BB * NN)
#define BLK 256
#define CSPLIT 4
#define CCHUNK (NN / CSPLIT)   // 512 candidates per block
#define QCHUNKS (NN / BLK)     // 8 query chunks per batch

// Workspace layout:
//   float  minarr[2*BN]                      bytes [0, 131072)
//   double acc[17] at byte offset 131072:
//     acc[0]      = l1 numerator sum
//     acc[1..8]   = chamsum[b] (both directions accumulated)
//     acc[9..16]  = valid count per batch
#define ACC_OFF_BYTES (2 * BN * 4)

__global__ __launch_bounds__(BLK) void k_init(float* minarr, double* acc) {
    int i = blockIdx.x * BLK + threadIdx.x;
    if (i < 2 * BN) minarr[i] = 3.402823466e38f;
    if (i < 17) acc[i] = 0.0;
}

__global__ __launch_bounds__(BLK) void k_l1(const float* __restrict__ pred,
                                            const float* __restrict__ target,
                                            const int* __restrict__ mask,
                                            double* acc) {
    // 64 blocks: 8 per batch, each covers 256 contiguous points of one batch
    int b = blockIdx.x >> 3;
    int i = ((blockIdx.x & 7) * BLK) + threadIdx.x;
    int gi = b * NN + i;
    float m = (float)mask[gi];
    const float* p = pred + (size_t)gi * 3;
    const float* t = target + (size_t)gi * 3;
    float v = (fabsf(p[0] - t[0]) + fabsf(p[1] - t[1]) + fabsf(p[2] - t[2])) * (1.0f / 3.0f) * m;
    // wave64 reduce both v and m
    for (int off = 32; off; off >>= 1) {
        v += __shfl_down(v, off, 64);
        m += __shfl_down(m, off, 64);
    }
    if ((threadIdx.x & 63) == 0) {
        atomicAdd(&acc[0], (double)v);
        atomicAdd(&acc[9 + b], (double)m);
    }
}

__global__ __launch_bounds__(BLK) void k_cham(const float* __restrict__ pred,
                                              const float* __restrict__ target,
                                              const float* __restrict__ points,
                                              const int* __restrict__ mask,
                                              float* minarr) {
    // blockIdx.x encodes: cs (4) | qc (8) | b (8) | task (2)  -> 512 blocks
    int bid = blockIdx.x;
    int cs = bid & (CSPLIT - 1);  bid >>= 2;
    int qc = bid & (QCHUNKS - 1); bid >>= 3;
    int b  = bid & 7;             bid >>= 3;
    int task = bid;  // 0: query=clean(points+target), cand=predp(points+pred)
                     // 1: query=predp,               cand=clean

    const float* dq = (task == 0) ? target : pred;  // query delta
    const float* dc = (task == 0) ? pred : target;  // candidate delta

    __shared__ float cx[CCHUNK], cy[CCHUNK], cz[CCHUNK];
    int c0 = cs * CCHUNK;
    for (int j = threadIdx.x; j < CCHUNK; j += BLK) {
        int g = b * NN + c0 + j;
        int mv = mask[g];
        size_t g3 = (size_t)g * 3;
        float x = points[g3 + 0] + dc[g3 + 0];
        float y = points[g3 + 1] + dc[g3 + 1];
        float z = points[g3 + 2] + dc[g3 + 2];
        if (!mv) { x = 1e30f; y = 1e30f; z = 1e30f; }  // loses every min; stays finite
        cx[j] = x; cy[j] = y; cz[j] = z;
    }
    __syncthreads();

    int qi = qc * BLK + threadIdx.x;
    int gq = b * NN + qi;
    size_t gq3 = (size_t)gq * 3;
    float qx = points[gq3 + 0] + dq[gq3 + 0];
    float qy = points[gq3 + 1] + dq[gq3 + 1];
    float qz = points[gq3 + 2] + dq[gq3 + 2];

    float mn = 3.402823466e38f;
    #pragma unroll 8
    for (int j = 0; j < CCHUNK; ++j) {
        float d = fabsf(qx - cx[j]) + fabsf(qy - cy[j]) + fabsf(qz - cz[j]);
        mn = fminf(mn, d);
    }
    // positive floats: uint compare == float compare
    atomicMin((unsigned int*)&minarr[task * BN + gq], __float_as_uint(mn));
}

__global__ __launch_bounds__(BLK) void k_wsum(const float* __restrict__ minarr,
                                              const int* __restrict__ mask,
                                              double* acc) {
    // 128 blocks over 2*BN mins; each block lies within one (task, batch)
    int g = blockIdx.x * BLK + threadIdx.x;
    int r = g & (BN - 1);          // index within task
    int b = r >> 11;               // N = 2048
    int i = r & (NN - 1);
    float v = minarr[g] * (float)mask[b * NN + i];
    for (int off = 32; off; off >>= 1) v += __shfl_down(v, off, 64);
    if ((threadIdx.x & 63) == 0) atomicAdd(&acc[1 + b], (double)v);
}

__global__ void k_fin(const double* __restrict__ acc, float* out) {
    if (threadIdx.x == 0) {
        double msum = 0.0;
        for (int b = 0; b < BB; ++b) msum += acc[9 + b];
        double l1 = acc[0] / msum;
        double cd = 0.0;
        for (int b = 0; b < BB; ++b) cd += acc[1 + b] / acc[9 + b];
        cd *= (1.0 / BB);
        out[0] = (float)(l1 + exp(-l1) * cd);
    }
}

extern "C" void kernel_launch(void* const* d_in, const int* in_sizes, int n_in,
                              void* d_out, int out_size, void* d_ws, size_t ws_size,
                              hipStream_t stream) {
    const float* pred   = (const float*)d_in[0];
    const float* target = (const float*)d_in[1];
    const int*   mask   = (const int*)d_in[2];
    const float* points = (const float*)d_in[3];
    float* out = (float*)d_out;

    float*  minarr = (float*)d_ws;
    double* acc    = (double*)((char*)d_ws + ACC_OFF_BYTES);

    k_init<<<(2 * BN + BLK - 1) / BLK, BLK, 0, stream>>>(minarr, acc);
    k_l1<<<BN / BLK, BLK, 0, stream>>>(pred, target, mask, acc);
    k_cham<<<2 * BB * QCHUNKS * CSPLIT, BLK, 0, stream>>>(pred, target, points, mask, minarr);
    k_wsum<<<2 * BN / BLK, BLK, 0, stream>>>(minarr, mask, acc);
    k_fin<<<1, 64, 0, stream>>>(acc, out);
}

// Round 2
// 30.537 us; speedup vs baseline: 2.0440x; 2.0440x over previous
//
#include <hip/hip_runtime.h>
#include <math.h>
#include <float.h>

// Problem constants (match reference setup_inputs)
#define BB 8
#define NN 2048
#define BN (BB * NN)
#define BLK 256
#define Q 8                    // queries per thread: 256*8 = 2048 = full batch
#define CSPLIT 32              // candidate splits per (task,batch)
#define CCHUNK (NN / CSPLIT)   // 64 candidates staged per block

// Workspace layout:
//   uint  minarr[2*BN]   @ 0        (float bits via uint atomicMin; init 0xFF)
//   float l1part[8]      @ 2*BN*4   (per-batch masked L1 numerator)
//   float cntpart[8]     @ +32      (per-batch valid count)

__global__ __launch_bounds__(BLK) void k_main(const float* __restrict__ pred,
                                              const float* __restrict__ target,
                                              const float* __restrict__ points,
                                              const int* __restrict__ mask,
                                              unsigned int* __restrict__ minarr,
                                              float* __restrict__ l1part,
                                              float* __restrict__ cntpart) {
    // bid bits: cs(5) | b(3) | task(1)  -> 512 blocks
    int bid = blockIdx.x;
    int cs = bid & (CSPLIT - 1);
    int b = (bid >> 5) & 7;
    int task = bid >> 8;   // 0: query=clean(points+target), cand=predp(points+pred)
                           // 1: query=predp,               cand=clean
    int t = threadIdx.x;

    const float* dq = task ? pred : target;   // query delta
    const float* dc = task ? target : pred;   // candidate delta

    __shared__ float4 cand[CCHUNK];
    if (t < CCHUNK) {
        int g = b * NN + cs * CCHUNK + t;
        size_t g3 = (size_t)g * 3;
        float x, y, z;
        if (mask[g]) {
            x = points[g3 + 0] + dc[g3 + 0];
            y = points[g3 + 1] + dc[g3 + 1];
            z = points[g3 + 2] + dc[g3 + 2];
        } else {
            x = y = z = 1e30f;  // loses every min; stays finite
        }
        cand[t] = make_float4(x, y, z, 0.f);
    }
    __syncthreads();

    float qx[Q], qy[Q], qz[Q], mn[Q];
    #pragma unroll
    for (int q = 0; q < Q; ++q) {
        int gi = b * NN + q * BLK + t;
        size_t g3 = (size_t)gi * 3;
        qx[q] = points[g3 + 0] + dq[g3 + 0];
        qy[q] = points[g3 + 1] + dq[g3 + 1];
        qz[q] = points[g3 + 2] + dq[g3 + 2];
        mn[q] = FLT_MAX;
    }

    #pragma unroll 4
    for (int j = 0; j < CCHUNK; ++j) {
        float4 c = cand[j];   // broadcast ds_read_b128, conflict-free
        #pragma unroll
        for (int q = 0; q < Q; ++q) {
            float d = fabsf(qx[q] - c.x) + fabsf(qy[q] - c.y) + fabsf(qz[q] - c.z);
            mn[q] = fminf(mn[q], d);
        }
    }

    // positive floats: uint compare == float compare
    #pragma unroll
    for (int q = 0; q < Q; ++q)
        atomicMin(&minarr[task * BN + b * NN + q * BLK + t], __float_as_uint(mn[q]));

    // Fused masked-L1 + valid-count: one block per batch does it (task0, cs0)
    if (task == 0 && cs == 0) {
        float s = 0.f, c = 0.f;
        #pragma unroll
        for (int q = 0; q < Q; ++q) {
            int gi = b * NN + q * BLK + t;
            size_t g3 = (size_t)gi * 3;
            float m = (float)mask[gi];
            s += (fabsf(pred[g3 + 0] - target[g3 + 0]) +
                  fabsf(pred[g3 + 1] - target[g3 + 1]) +
                  fabsf(pred[g3 + 2] - target[g3 + 2])) * (1.0f / 3.0f) * m;
            c += m;
        }
        for (int off = 32; off; off >>= 1) {
            s += __shfl_down(s, off, 64);
            c += __shfl_down(c, off, 64);
        }
        __shared__ float ls[4], lc[4];
        if ((t & 63) == 0) { ls[t >> 6] = s; lc[t >> 6] = c; }
        __syncthreads();
        if (t == 0) {
            l1part[b]  = ls[0] + ls[1] + ls[2] + ls[3];
            cntpart[b] = lc[0] + lc[1] + lc[2] + lc[3];
        }
    }
}

__global__ __launch_bounds__(1024) void k_final(const unsigned int* __restrict__ minarr,
                                                const int* __restrict__ mask,
                                                const float* __restrict__ l1part,
                                                const float* __restrict__ cntpart,
                                                float* __restrict__ out) {
    int t = threadIdx.x;
    const float* mf = (const float*)minarr;  // stored bits are valid positive floats
    int g0 = t * 32;                 // 1024 threads x 32 = 2*BN, within one (task,b)
    int m0 = g0 & (BN - 1);          // mask index (shared across tasks)
    float v = 0.f;
    #pragma unroll 8
    for (int k = 0; k < 32; ++k)
        v += mf[g0 + k] * (float)mask[m0 + k];
    for (int off = 32; off; off >>= 1) v += __shfl_down(v, off, 64);

    // wave w covers exactly one (task,b): task = w>>3, b = w&7
    __shared__ float cham[16];
    if ((t & 63) == 0) cham[t >> 6] = v;
    __syncthreads();

    if (t == 0) {
        double msum = 0.0, l1num = 0.0;
        for (int b = 0; b < BB; ++b) { msum += cntpart[b]; l1num += l1part[b]; }
        double l1 = l1num / msum;
        double cd = 0.0;
        for (int b = 0; b < BB; ++b)
            cd += (double)(cham[b] + cham[8 + b]) / (double)cntpart[b];
        cd *= (1.0 / BB);
        out[0] = (float)(l1 + exp(-l1) * cd);
    }
}

extern "C" void kernel_launch(void* const* d_in, const int* in_sizes, int n_in,
                              void* d_out, int out_size, void* d_ws, size_t ws_size,
                              hipStream_t stream) {
    const float* pred   = (const float*)d_in[0];
    const float* target = (const float*)d_in[1];
    const int*   mask   = (const int*)d_in[2];
    const float* points = (const float*)d_in[3];
    float* out = (float*)d_out;

    unsigned int* minarr = (unsigned int*)d_ws;
    float* l1part  = (float*)((char*)d_ws + (size_t)2 * BN * 4);
    float* cntpart = l1part + 8;

    // 0xFFFFFFFF == UINT_MAX: identity for uint atomicMin on positive-float bits
    hipMemsetAsync(minarr, 0xFF, (size_t)2 * BN * sizeof(unsigned int), stream);
    k_main<<<2 * BB * CSPLIT, BLK, 0, stream>>>(pred, target, points, mask,
                                                minarr, l1part, cntpart);
    k_final<<<1, 1024, 0, stream>>>(minarr, mask, l1part, cntpart, out);
}

// Round 3
// 21.852 us; speedup vs baseline: 2.8564x; 1.3975x over previous
//
#include <hip/hip_runtime.h>
#include <math.h>
#include <float.h>

// Problem constants (match reference setup_inputs)
#define BB 8
#define NN 2048
#define BN (BB * NN)
#define BLK 256
#define Q 4                     // queries per thread
#define QSPLIT 2                // query-chunks per (task,b): 2 * (256*4) = 2048
#define CSPLIT 32               // candidate splits per (task,batch)
#define CCHUNK (NN / CSPLIT)    // 64 candidates staged per block

// Workspace layout (all slots fully written every call; no init needed):
//   float minpart[CSPLIT][2*BN]        @ 0            (4 MB)
//   float champart[64]                 @ 4 MB
//   float l1part[16]                   @ +256
//   float cntpart[16]                  @ +320
#define MINPART_FLOATS (CSPLIT * 2 * BN)

__global__ __launch_bounds__(BLK) void k_main(const float* __restrict__ pred,
                                              const float* __restrict__ target,
                                              const float* __restrict__ points,
                                              const int* __restrict__ mask,
                                              float* __restrict__ minpart,
                                              float* __restrict__ l1part,
                                              float* __restrict__ cntpart) {
    // bid bits: cs(5) | qs(1) | b(3) | task(1)  -> 1024 blocks
    int bid = blockIdx.x;
    int cs = bid & (CSPLIT - 1);
    int qs = (bid >> 5) & (QSPLIT - 1);
    int b = (bid >> 6) & 7;
    int task = bid >> 9;   // 0: query=clean(points+target), cand=predp(points+pred)
                           // 1: query=predp,               cand=clean
    int t = threadIdx.x;

    const float* dq = task ? pred : target;   // query delta
    const float* dc = task ? target : pred;   // candidate delta

    __shared__ float4 cand[CCHUNK];
    if (t < CCHUNK) {
        int g = b * NN + cs * CCHUNK + t;
        size_t g3 = (size_t)g * 3;
        float x, y, z;
        if (mask[g]) {
            x = points[g3 + 0] + dc[g3 + 0];
            y = points[g3 + 1] + dc[g3 + 1];
            z = points[g3 + 2] + dc[g3 + 2];
        } else {
            x = y = z = 1e30f;  // loses every min; stays finite
        }
        cand[t] = make_float4(x, y, z, 0.f);
    }
    __syncthreads();

    float qx[Q], qy[Q], qz[Q], mn[Q];
    #pragma unroll
    for (int q = 0; q < Q; ++q) {
        int qi = qs * (BLK * Q) + q * BLK + t;
        size_t g3 = (size_t)(b * NN + qi) * 3;
        qx[q] = points[g3 + 0] + dq[g3 + 0];
        qy[q] = points[g3 + 1] + dq[g3 + 1];
        qz[q] = points[g3 + 2] + dq[g3 + 2];
        mn[q] = FLT_MAX;
    }

    #pragma unroll 4
    for (int j = 0; j < CCHUNK; ++j) {
        float4 c = cand[j];   // broadcast ds_read_b128, conflict-free
        #pragma unroll
        for (int q = 0; q < Q; ++q) {
            float d = fabsf(qx[q] - c.x) + fabsf(qy[q] - c.y) + fabsf(qz[q] - c.z);
            mn[q] = fminf(mn[q], d);
        }
    }

    // non-atomic partial-min store: one distinct slot per (cs, task, b, query)
    float* mp = minpart + (size_t)cs * (2 * BN) + (size_t)task * BN + b * NN;
    #pragma unroll
    for (int q = 0; q < Q; ++q)
        mp[qs * (BLK * Q) + q * BLK + t] = mn[q];

    // Fused masked-L1 + valid-count: (task0, cs0) blocks, one per (b, qs)
    if (task == 0 && cs == 0) {
        float s = 0.f, c = 0.f;
        #pragma unroll
        for (int q = 0; q < Q; ++q) {
            int gi = b * NN + qs * (BLK * Q) + q * BLK + t;
            size_t g3 = (size_t)gi * 3;
            float m = (float)mask[gi];
            s += (fabsf(pred[g3 + 0] - target[g3 + 0]) +
                  fabsf(pred[g3 + 1] - target[g3 + 1]) +
                  fabsf(pred[g3 + 2] - target[g3 + 2])) * (1.0f / 3.0f) * m;
            c += m;
        }
        for (int off = 32; off; off >>= 1) {
            s += __shfl_down(s, off, 64);
            c += __shfl_down(c, off, 64);
        }
        __shared__ float ls[4], lc[4];
        if ((t & 63) == 0) { ls[t >> 6] = s; lc[t >> 6] = c; }
        __syncthreads();
        if (t == 0) {
            l1part[b * QSPLIT + qs]  = ls[0] + ls[1] + ls[2] + ls[3];
            cntpart[b * QSPLIT + qs] = lc[0] + lc[1] + lc[2] + lc[3];
        }
    }
}

__global__ __launch_bounds__(BLK) void k_reduce(const float* __restrict__ minpart,
                                                const int* __restrict__ mask,
                                                float* __restrict__ champart) {
    // 64 blocks: task(1) | b(3) | qs(2); each covers 512 queries, thread does 2
    int tb = blockIdx.x;
    int qs = tb & 3;
    int b = (tb >> 2) & 7;
    int task = tb >> 5;
    int t = threadIdx.x;

    float v = 0.f;
    #pragma unroll
    for (int k = 0; k < 2; ++k) {
        int qi = qs * 512 + k * BLK + t;
        size_t idx = (size_t)task * BN + b * NN + qi;
        float mn = minpart[idx];
        #pragma unroll
        for (int cs = 1; cs < CSPLIT; ++cs)
            mn = fminf(mn, minpart[(size_t)cs * (2 * BN) + idx]);
        v += mn * (float)mask[b * NN + qi];
    }
    for (int off = 32; off; off >>= 1) v += __shfl_down(v, off, 64);
    __shared__ float ls[4];
    if ((t & 63) == 0) ls[t >> 6] = v;
    __syncthreads();
    if (t == 0) champart[tb] = ls[0] + ls[1] + ls[2] + ls[3];
}

__global__ void k_fin(const float* __restrict__ champart,
                      const float* __restrict__ l1part,
                      const float* __restrict__ cntpart,
                      float* __restrict__ out) {
    if (threadIdx.x == 0) {
        double cnt[BB], msum = 0.0, l1num = 0.0;
        for (int b = 0; b < BB; ++b) {
            cnt[b] = (double)cntpart[2 * b] + (double)cntpart[2 * b + 1];
            msum += cnt[b];
            l1num += (double)l1part[2 * b] + (double)l1part[2 * b + 1];
        }
        double l1 = l1num / msum;
        double cd = 0.0;
        for (int b = 0; b < BB; ++b) {
            double ch = 0.0;
            for (int qs = 0; qs < 4; ++qs)
                ch += (double)champart[(b << 2) + qs] + (double)champart[32 + (b << 2) + qs];
            cd += ch / cnt[b];
        }
        cd *= (1.0 / BB);
        out[0] = (float)(l1 + exp(-l1) * cd);
    }
}

extern "C" void kernel_launch(void* const* d_in, const int* in_sizes, int n_in,
                              void* d_out, int out_size, void* d_ws, size_t ws_size,
                              hipStream_t stream) {
    const float* pred   = (const float*)d_in[0];
    const float* target = (const float*)d_in[1];
    const int*   mask   = (const int*)d_in[2];
    const float* points = (const float*)d_in[3];
    float* out = (float*)d_out;

    float* minpart  = (float*)d_ws;
    float* champart = (float*)((char*)d_ws + (size_t)MINPART_FLOATS * 4);
    float* l1part   = champart + 64;
    float* cntpart  = l1part + 16;

    k_main<<<2 * 8 * QSPLIT * CSPLIT, BLK, 0, stream>>>(pred, target, points, mask,
                                                        minpart, l1part, cntpart);
    k_reduce<<<64, BLK, 0, stream>>>(minpart, mask, champart);
    k_fin<<<1, 64, 0, stream>>>(champart, l1part, cntpart, out);
}